// Round 5
// baseline (108.629 us; speedup 1.0000x reference)
//
#include <hip/hip_runtime.h>
#include <hip/hip_fp16.h>
#include <stdint.h>

#define D0 1024
#define D1 8192
#define D2 8192
#define D3 10240
#define B_ROWS 4096

// LDS layout (bytes): xb at 0 (zero-add BC gathers), h2 at 8192 (stage-D
// gathers fold 8192 into the 16-bit ds offset immediate), csum after.
// 72.2 KB -> 2 blocks/CU, 32 waves/CU.
#define SM_XB     0
#define SM_H2     8192
#define SM_CSUM   (8192 + 65536)
#define SM_BYTES  (8192 + 65536 + 160)

// softmax(w[16]) @ OP_COEF -> (c0,c1,c2,c3)
__device__ __forceinline__ float4 softmax_coef(const float* __restrict__ w) {
    const float4* wv = (const float4*)w;
    float4 q0 = wv[0], q1 = wv[1], q2 = wv[2], q3 = wv[3];
    float wa[16] = {q0.x, q0.y, q0.z, q0.w, q1.x, q1.y, q1.z, q1.w,
                    q2.x, q2.y, q2.z, q2.w, q3.x, q3.y, q3.z, q3.w};
    float m = wa[0];
#pragma unroll
    for (int i = 1; i < 16; ++i) m = fmaxf(m, wa[i]);
    float e[16], s = 0.f;
#pragma unroll
    for (int i = 0; i < 16; ++i) { e[i] = __expf(wa[i] - m); s += e[i]; }
    float inv = 1.f / s;
    static constexpr float OPC[16][4] = {
        {0.f, 0.f, 0.f, 0.f}, {0.f, 0.f, 0.f, 1.f}, {0.f, 1.f, 0.f, -1.f}, {0.f, 1.f, 0.f, 0.f},
        {0.f, 0.f, 1.f, -1.f}, {0.f, 0.f, 1.f, 0.f}, {0.f, 1.f, 1.f, -2.f}, {0.f, 1.f, 1.f, -1.f},
        {1.f, -1.f, -1.f, 1.f}, {1.f, -1.f, -1.f, 2.f}, {1.f, 0.f, -1.f, 0.f}, {1.f, 0.f, -1.f, 1.f},
        {1.f, -1.f, 0.f, 0.f}, {1.f, -1.f, 0.f, 1.f}, {1.f, 0.f, 0.f, -1.f}, {1.f, 0.f, 0.f, 0.f}};
    float c0 = 0.f, c1 = 0.f, c2 = 0.f, c3 = 0.f;
#pragma unroll
    for (int i = 0; i < 16; ++i) {  // 0/±1/±2 multiplies fold at compile time
        float p = e[i] * inv;
        c0 += p * OPC[i][0];
        c1 += p * OPC[i][1];
        c2 += p * OPC[i][2];
        c3 += p * OPC[i][3];
    }
    return make_float4(c0, c1, c2, c3);
}

__device__ __forceinline__ uint2 pack_coef(float4 c) {
    uint2 r;
    r.x = __builtin_bit_cast(uint32_t, __floats2half2_rn(c.x, c.y));
    r.y = __builtin_bit_cast(uint32_t, __floats2half2_rn(c.z, c.w));
    return r;
}

// prep: bakes run-invariant metadata (layer-1 fused into layer-2 records).
__global__ __launch_bounds__(64) void prep_kernel(
    const float* __restrict__ w1, const float* __restrict__ w2,
    const float* __restrict__ w3,
    const int* __restrict__ ia1, const int* __restrict__ ib1,
    const int* __restrict__ ia2, const int* __restrict__ ib2,
    const int* __restrict__ ia3, const int* __restrict__ ib3,
    uint2* __restrict__ bcIdx, uint4* __restrict__ bcCoefAB,
    uint2* __restrict__ bcCoefO, uint32_t* __restrict__ d3Idx,
    uint2* __restrict__ d3Coef) {
    int G = blockIdx.x * 64 + threadIdx.x;  // grid = (D2 + D3) / 64
    if (G < D2) {
        int g = G;
        int pa = ia2[g], pb = ib2[g];
        float4 cO = softmax_coef(w2 + (size_t)g * 16);
        float4 cA = softmax_coef(w1 + (size_t)pa * 16);
        float4 cB = softmax_coef(w1 + (size_t)pb * 16);
        uint2 xi;
        xi.x = (uint32_t)(ia1[pa] << 3) | ((uint32_t)(ib1[pa] << 3) << 16);
        xi.y = (uint32_t)(ia1[pb] << 3) | ((uint32_t)(ib1[pb] << 3) << 16);
        bcIdx[g] = xi;
        uint2 a = pack_coef(cA), b = pack_coef(cB);
        bcCoefAB[g] = make_uint4(a.x, a.y, b.x, b.y);
        bcCoefO[g] = pack_coef(cO);
    } else {
        int g = G - D2;
        float4 cO = softmax_coef(w3 + (size_t)g * 16);
        d3Idx[g] = (uint32_t)(ia3[g] << 3) | ((uint32_t)(ib3[g] << 3) << 16);
        d3Coef[g] = pack_coef(cO);
    }
}

// One gate for 4 rows (2x half2); compact coefs (c0c1, c2c3) broadcast here.
__device__ __forceinline__ uint2 gate4(uint2 av, uint2 bv, uint2 cf) {
    __half2 p = __builtin_bit_cast(__half2, cf.x);  // (c0,c1)
    __half2 q = __builtin_bit_cast(__half2, cf.y);  // (c2,c3)
    __half2 c0 = __low2half2(p), c1 = __high2half2(p);
    __half2 c2 = __low2half2(q), c3 = __high2half2(q);
    __half2 a01 = __builtin_bit_cast(__half2, av.x);
    __half2 a23 = __builtin_bit_cast(__half2, av.y);
    __half2 b01 = __builtin_bit_cast(__half2, bv.x);
    __half2 b23 = __builtin_bit_cast(__half2, bv.y);
    __half2 h01 = __hfma2(a01, __hfma2(b01, c3, c1), __hfma2(b01, c2, c0));
    __half2 h23 = __hfma2(a23, __hfma2(b23, c3, c1), __hfma2(b23, c2, c0));
    uint2 r;
    r.x = __builtin_bit_cast(uint32_t, h01);
    r.y = __builtin_bit_cast(uint32_t, h23);
    return r;
}

// Fused kernel: layers 1+2 fused, then layer 3 + group-sum. One block = 4
// rows, activations row-interleaved fp16 [gate][4rows]. All metadata streams
// are software-pipelined (depth 2) so each iteration's L2 latency drains
// under the previous iteration's LDS+VALU work. Keeping VGPR <= 64 preserves
// 2 blocks/CU (32 waves) -- hence depth 2, not full unrolled prefetch.
__global__ __launch_bounds__(1024, 8) void fused_kernel(
    const float* __restrict__ x, const uint2* __restrict__ bcIdx,
    const uint4* __restrict__ bcCoefAB, const uint2* __restrict__ bcCoefO,
    const uint32_t* __restrict__ d3Idx, const uint2* __restrict__ d3Coef,
    float* __restrict__ out) {
    extern __shared__ char sm[];
    uint2* xb = (uint2*)(sm + SM_XB);
    uint2* h2 = (uint2*)(sm + SM_H2);
    float* csum = (float*)(sm + SM_CSUM);

    const int t = threadIdx.x;
    const int rowbase = blockIdx.x << 2;

    // Preload BC iter-0 metadata: latency hidden behind stage A + barrier.
    uint2 xi_n = bcIdx[t];
    uint4 cab_n = bcCoefAB[t];
    uint2 co_n = bcCoefO[t];

    // Stage A: 4 rows of x -> fp16, row-interleaved into xb.
    {
        const float* xp = x + (size_t)rowbase * D0 + t;
        float v0 = xp[0];
        float v1 = xp[D0];
        float v2 = xp[2 * D0];
        float v3 = xp[3 * D0];
        uint2 v;
        v.x = __builtin_bit_cast(uint32_t, __floats2half2_rn(v0, v1));
        v.y = __builtin_bit_cast(uint32_t, __floats2half2_rn(v2, v3));
        xb[t] = v;
    }
    if (t < 40) csum[t] = 0.f;
    __syncthreads();

    // Stage BC: fused layers 1+2, metadata double-buffered.
#pragma unroll
    for (int k = 0; k < 8; ++k) {
        uint2 xi = xi_n;
        uint4 cab = cab_n;
        uint2 co = co_n;
        if (k < 7) {  // issue next iteration's loads before consuming current
            int gn = t + ((k + 1) << 10);
            xi_n = bcIdx[gn];
            cab_n = bcCoefAB[gn];
            co_n = bcCoefO[gn];
        }
        uint2 aa = *(const uint2*)(sm + (xi.x & 0xffffu));
        uint2 ab = *(const uint2*)(sm + (xi.x >> 16));
        uint2 ba = *(const uint2*)(sm + (xi.y & 0xffffu));
        uint2 bb = *(const uint2*)(sm + (xi.y >> 16));
        uint2 ha = gate4(aa, ab, make_uint2(cab.x, cab.y));
        uint2 hb = gate4(ba, bb, make_uint2(cab.z, cab.w));
        h2[t + (k << 10)] = gate4(ha, hb, co);
    }

    // Preload D iter-0 metadata before the barrier.
    const int wv = t >> 6, lane = t & 63;
    const int gbase = wv * 640;
    uint32_t ip_n = d3Idx[gbase + lane];
    uint2 cf_n = d3Coef[gbase + lane];
    __syncthreads();

    // Stage D: layer 3 + grouped sum. Each wave owns 640 contiguous gates
    // (spans <=2 classes; 64-gate chunks never straddle a class boundary).
    {
        const int cA = gbase >> 10;
        const int bnd = (cA + 1) << 10;
        float s0[4] = {0.f, 0.f, 0.f, 0.f};
        float s1[4] = {0.f, 0.f, 0.f, 0.f};
#pragma unroll
        for (int j = 0; j < 10; ++j) {
            uint32_t ip = ip_n;
            uint2 cf = cf_n;
            if (j < 9) {
                int gn = gbase + ((j + 1) << 6) + lane;
                ip_n = d3Idx[gn];
                cf_n = d3Coef[gn];
            }
            int gc = gbase + (j << 6);
            uint2 av = *(const uint2*)(sm + SM_H2 + (ip & 0xffffu));
            uint2 bv = *(const uint2*)(sm + SM_H2 + (ip >> 16));
            uint2 hv = gate4(av, bv, cf);
            __half2 h01 = __builtin_bit_cast(__half2, hv.x);
            __half2 h23 = __builtin_bit_cast(__half2, hv.y);
            float f0 = __low2float(h01), f1 = __high2float(h01);
            float f2 = __low2float(h23), f3 = __high2float(h23);
            if (gc < bnd) {
                s0[0] += f0; s0[1] += f1; s0[2] += f2; s0[3] += f3;
            } else {
                s1[0] += f0; s1[1] += f1; s1[2] += f2; s1[3] += f3;
            }
        }
#pragma unroll
        for (int m = 1; m < 64; m <<= 1) {
#pragma unroll
            for (int r = 0; r < 4; ++r) {
                s0[r] += __shfl_xor(s0[r], m, 64);
                s1[r] += __shfl_xor(s1[r], m, 64);
            }
        }
        if (lane == 0) {
#pragma unroll
            for (int r = 0; r < 4; ++r) atomicAdd(&csum[cA * 4 + r], s0[r]);
            if (gbase + 640 > bnd) {
#pragma unroll
                for (int r = 0; r < 4; ++r) atomicAdd(&csum[(cA + 1) * 4 + r], s1[r]);
            }
        }
    }
    __syncthreads();

    if (t < 40) {
        int c = t >> 2, r = t & 3;
        out[(size_t)(rowbase + r) * 10 + c] = csum[t] * (1.0f / 30.0f);
    }
}

extern "C" void kernel_launch(void* const* d_in, const int* in_sizes, int n_in,
                              void* d_out, int out_size, void* d_ws, size_t ws_size,
                              hipStream_t stream) {
    const float* x = (const float*)d_in[0];
    const float* w1 = (const float*)d_in[1];
    const float* w2 = (const float*)d_in[2];
    const float* w3 = (const float*)d_in[3];
    const int* ia1 = (const int*)d_in[4];
    const int* ib1 = (const int*)d_in[5];
    const int* ia2 = (const int*)d_in[6];
    const int* ib2 = (const int*)d_in[7];
    const int* ia3 = (const int*)d_in[8];
    const int* ib3 = (const int*)d_in[9];
    float* out = (float*)d_out;

    // Workspace: bcIdx 64K | bcCoefAB 128K | bcCoefO 64K | d3Idx 40K | d3Coef 80K
    char* p = (char*)d_ws;
    uint2* bcIdx = (uint2*)p;                 p += (size_t)D2 * 8;
    uint4* bcCoefAB = (uint4*)p;              p += (size_t)D2 * 16;
    uint2* bcCoefO = (uint2*)p;               p += (size_t)D2 * 8;
    uint32_t* d3Idx = (uint32_t*)p;           p += (size_t)D3 * 4;
    uint2* d3Coef = (uint2*)p;

    // >64KB dynamic LDS opt-in (host-side; graph-capture safe).
    hipFuncSetAttribute(reinterpret_cast<const void*>(fused_kernel),
                        hipFuncAttributeMaxDynamicSharedMemorySize, SM_BYTES);

    prep_kernel<<<(D2 + D3) / 64, 64, 0, stream>>>(
        w1, w2, w3, ia1, ib1, ia2, ib2, ia3, ib3,
        bcIdx, bcCoefAB, bcCoefO, d3Idx, d3Coef);
    fused_kernel<<<B_ROWS / 4, 1024, SM_BYTES, stream>>>(
        x, bcIdx, bcCoefAB, bcCoefO, d3Idx, d3Coef, out);
}

// Round 6
// 106.893 us; speedup vs baseline: 1.0162x; 1.0162x over previous
//
#include <hip/hip_runtime.h>
#include <hip/hip_fp16.h>
#include <stdint.h>

#define D0 1024
#define D1 8192
#define D2 8192
#define D3 10240
#define B_ROWS 4096

// LDS layout (bytes): xb at 0 (zero-add BC gathers), h2 at 8192, csum after.
// 72.2 KB -> 2 blocks/CU, 32 waves/CU.
#define SM_XB     0
#define SM_H2     8192
#define SM_CSUM   (8192 + 65536)
#define SM_BYTES  (8192 + 65536 + 160)

// softmax(w[16]) @ OP_COEF -> (c0,c1,c2,c3)
__device__ __forceinline__ float4 softmax_coef(const float* __restrict__ w) {
    const float4* wv = (const float4*)w;
    float4 q0 = wv[0], q1 = wv[1], q2 = wv[2], q3 = wv[3];
    float wa[16] = {q0.x, q0.y, q0.z, q0.w, q1.x, q1.y, q1.z, q1.w,
                    q2.x, q2.y, q2.z, q2.w, q3.x, q3.y, q3.z, q3.w};
    float m = wa[0];
#pragma unroll
    for (int i = 1; i < 16; ++i) m = fmaxf(m, wa[i]);
    float e[16], s = 0.f;
#pragma unroll
    for (int i = 0; i < 16; ++i) { e[i] = __expf(wa[i] - m); s += e[i]; }
    float inv = 1.f / s;
    static constexpr float OPC[16][4] = {
        {0.f, 0.f, 0.f, 0.f}, {0.f, 0.f, 0.f, 1.f}, {0.f, 1.f, 0.f, -1.f}, {0.f, 1.f, 0.f, 0.f},
        {0.f, 0.f, 1.f, -1.f}, {0.f, 0.f, 1.f, 0.f}, {0.f, 1.f, 1.f, -2.f}, {0.f, 1.f, 1.f, -1.f},
        {1.f, -1.f, -1.f, 1.f}, {1.f, -1.f, -1.f, 2.f}, {1.f, 0.f, -1.f, 0.f}, {1.f, 0.f, -1.f, 1.f},
        {1.f, -1.f, 0.f, 0.f}, {1.f, -1.f, 0.f, 1.f}, {1.f, 0.f, 0.f, -1.f}, {1.f, 0.f, 0.f, 0.f}};
    float c0 = 0.f, c1 = 0.f, c2 = 0.f, c3 = 0.f;
#pragma unroll
    for (int i = 0; i < 16; ++i) {  // 0/±1/±2 multiplies fold at compile time
        float p = e[i] * inv;
        c0 += p * OPC[i][0];
        c1 += p * OPC[i][1];
        c2 += p * OPC[i][2];
        c3 += p * OPC[i][3];
    }
    return make_float4(c0, c1, c2, c3);
}

__device__ __forceinline__ uint2 pack_coef(float4 c) {
    uint2 r;
    r.x = __builtin_bit_cast(uint32_t, __floats2half2_rn(c.x, c.y));
    r.y = __builtin_bit_cast(uint32_t, __floats2half2_rn(c.z, c.w));
    return r;
}

// prep: bakes run-invariant metadata, packed for single-dwordx4 consumption.
//  bcM1[g] = (xiA, xiB, coO.lo, coO.hi)   xi* = packed x byte-offsets of the
//  bcM2[g] = (cA.lo, cA.hi, cB.lo, cB.hi) two fused layer-1 parents
//  d3M[g]  = (xi, co.lo, co.hi, 0)        xi = packed h2 byte-offsets
__global__ __launch_bounds__(64) void prep_kernel(
    const float* __restrict__ w1, const float* __restrict__ w2,
    const float* __restrict__ w3,
    const int* __restrict__ ia1, const int* __restrict__ ib1,
    const int* __restrict__ ia2, const int* __restrict__ ib2,
    const int* __restrict__ ia3, const int* __restrict__ ib3,
    uint4* __restrict__ bcM1, uint4* __restrict__ bcM2,
    uint4* __restrict__ d3M) {
    int G = blockIdx.x * 64 + threadIdx.x;  // grid = (D2 + D3) / 64
    if (G < D2) {
        int g = G;
        int pa = ia2[g], pb = ib2[g];
        float4 cO = softmax_coef(w2 + (size_t)g * 16);
        float4 cA = softmax_coef(w1 + (size_t)pa * 16);
        float4 cB = softmax_coef(w1 + (size_t)pb * 16);
        uint32_t xiA = (uint32_t)(ia1[pa] << 3) | ((uint32_t)(ib1[pa] << 3) << 16);
        uint32_t xiB = (uint32_t)(ia1[pb] << 3) | ((uint32_t)(ib1[pb] << 3) << 16);
        uint2 o = pack_coef(cO), a = pack_coef(cA), b = pack_coef(cB);
        bcM1[g] = make_uint4(xiA, xiB, o.x, o.y);
        bcM2[g] = make_uint4(a.x, a.y, b.x, b.y);
    } else {
        int g = G - D2;
        float4 cO = softmax_coef(w3 + (size_t)g * 16);
        uint2 o = pack_coef(cO);
        uint32_t xi = (uint32_t)(ia3[g] << 3) | ((uint32_t)(ib3[g] << 3) << 16);
        d3M[g] = make_uint4(xi, o.x, o.y, 0u);
    }
}

// One gate for 4 rows (2x half2); compact coefs (c0c1, c2c3) broadcast here.
__device__ __forceinline__ uint2 gate4(uint2 av, uint2 bv, uint2 cf) {
    __half2 p = __builtin_bit_cast(__half2, cf.x);  // (c0,c1)
    __half2 q = __builtin_bit_cast(__half2, cf.y);  // (c2,c3)
    __half2 c0 = __low2half2(p), c1 = __high2half2(p);
    __half2 c2 = __low2half2(q), c3 = __high2half2(q);
    __half2 a01 = __builtin_bit_cast(__half2, av.x);
    __half2 a23 = __builtin_bit_cast(__half2, av.y);
    __half2 b01 = __builtin_bit_cast(__half2, bv.x);
    __half2 b23 = __builtin_bit_cast(__half2, bv.y);
    __half2 h01 = __hfma2(a01, __hfma2(b01, c3, c1), __hfma2(b01, c2, c0));
    __half2 h23 = __hfma2(a23, __hfma2(b23, c3, c1), __hfma2(b23, c2, c0));
    uint2 r;
    r.x = __builtin_bit_cast(uint32_t, h01);
    r.y = __builtin_bit_cast(uint32_t, h23);
    return r;
}

// Fused: layers 1+2 fused, then layer 3 + group-sum. One block = 4 rows,
// activations row-interleaved fp16 [gate][4rows]. Each thread handles a PAIR
// of adjacent gates per iteration: 8 independent LDS gathers in flight (2x
// the per-wave MLP of the single-gate loop), paired ds_write_b128 stores,
// and 16B-packed metadata. Index stream depth-2 prefetched.
__global__ __launch_bounds__(1024, 8) void fused_kernel(
    const float* __restrict__ x, const uint4* __restrict__ bcM1,
    const uint4* __restrict__ bcM2, const uint4* __restrict__ d3M,
    float* __restrict__ out) {
    extern __shared__ char sm[];
    uint2* xb = (uint2*)(sm + SM_XB);
    float* csum = (float*)(sm + SM_CSUM);

    const int t = threadIdx.x;
    const int rowbase = blockIdx.x << 2;
    const int tg = t << 1;  // first gate of this thread's pair

    // Preload iter-0 index metadata (latency hidden behind stage A + barrier).
    uint4 m1a_n = bcM1[tg];
    uint4 m1b_n = bcM1[tg + 1];

    // Stage A: 4 rows of x -> fp16, row-interleaved into xb.
    {
        const float* xp = x + (size_t)rowbase * D0 + t;
        float v0 = xp[0];
        float v1 = xp[D0];
        float v2 = xp[2 * D0];
        float v3 = xp[3 * D0];
        uint2 v;
        v.x = __builtin_bit_cast(uint32_t, __floats2half2_rn(v0, v1));
        v.y = __builtin_bit_cast(uint32_t, __floats2half2_rn(v2, v3));
        xb[t] = v;
    }
    if (t < 40) csum[t] = 0.f;
    __syncthreads();

    // Stage BC: fused layers 1+2, 2 gates/thread/iter, 4 iters covers 8192.
#pragma unroll
    for (int k = 0; k < 4; ++k) {
        uint4 m1a = m1a_n, m1b = m1b_n;
        int g = tg + (k << 11);
        uint4 m2a = bcM2[g];
        uint4 m2b = bcM2[g + 1];
        if (k < 3) {  // depth-2 prefetch of the gather-address stream
            int gn = tg + ((k + 1) << 11);
            m1a_n = bcM1[gn];
            m1b_n = bcM1[gn + 1];
        }
        // 8 independent gathers in flight.
        uint2 aa0 = *(const uint2*)(sm + (m1a.x & 0xffffu));
        uint2 ab0 = *(const uint2*)(sm + (m1a.x >> 16));
        uint2 ba0 = *(const uint2*)(sm + (m1a.y & 0xffffu));
        uint2 bb0 = *(const uint2*)(sm + (m1a.y >> 16));
        uint2 aa1 = *(const uint2*)(sm + (m1b.x & 0xffffu));
        uint2 ab1 = *(const uint2*)(sm + (m1b.x >> 16));
        uint2 ba1 = *(const uint2*)(sm + (m1b.y & 0xffffu));
        uint2 bb1 = *(const uint2*)(sm + (m1b.y >> 16));
        uint2 h0 = gate4(gate4(aa0, ab0, make_uint2(m2a.x, m2a.y)),
                         gate4(ba0, bb0, make_uint2(m2a.z, m2a.w)),
                         make_uint2(m1a.z, m1a.w));
        uint2 h1v = gate4(gate4(aa1, ab1, make_uint2(m2b.x, m2b.y)),
                          gate4(ba1, bb1, make_uint2(m2b.z, m2b.w)),
                          make_uint2(m1b.z, m1b.w));
        // Paired store: gates (g, g+1) = 16 contiguous bytes.
        ((uint4*)(sm + SM_H2))[(k << 10) + t] = make_uint4(h0.x, h0.y, h1v.x, h1v.y);
    }
    __syncthreads();

    // Stage D: layer 3 + grouped sum, 2 gates/lane/iter, 5 iters x 128 gates.
    // Each 128-gate chunk lies entirely within one class (128 | 1024).
    {
        const int wv = t >> 6, lane = t & 63;
        const int gbase = wv * 640;
        const int cA = gbase >> 10;
        const int bnd = (cA + 1) << 10;
        float s0[4] = {0.f, 0.f, 0.f, 0.f};
        float s1[4] = {0.f, 0.f, 0.f, 0.f};
#pragma unroll
        for (int j = 0; j < 5; ++j) {
            int gc = gbase + (j << 7);
            int g = gc + (lane << 1);
            uint4 ma = d3M[g];
            uint4 mb = d3M[g + 1];
            uint2 av0 = *(const uint2*)(sm + SM_H2 + (ma.x & 0xffffu));
            uint2 bv0 = *(const uint2*)(sm + SM_H2 + (ma.x >> 16));
            uint2 av1 = *(const uint2*)(sm + SM_H2 + (mb.x & 0xffffu));
            uint2 bv1 = *(const uint2*)(sm + SM_H2 + (mb.x >> 16));
            uint2 h0 = gate4(av0, bv0, make_uint2(ma.y, ma.z));
            uint2 h1v = gate4(av1, bv1, make_uint2(mb.y, mb.z));
            // Pairwise fp16 add of the two gates (values in [0,1] -> exact
            // enough), then one fp32 conversion per row.
            __half2 p01 = __hadd2(__builtin_bit_cast(__half2, h0.x),
                                  __builtin_bit_cast(__half2, h1v.x));
            __half2 p23 = __hadd2(__builtin_bit_cast(__half2, h0.y),
                                  __builtin_bit_cast(__half2, h1v.y));
            float f0 = __low2float(p01), f1 = __high2float(p01);
            float f2 = __low2float(p23), f3 = __high2float(p23);
            if (gc < bnd) {
                s0[0] += f0; s0[1] += f1; s0[2] += f2; s0[3] += f3;
            } else {
                s1[0] += f0; s1[1] += f1; s1[2] += f2; s1[3] += f3;
            }
        }
#pragma unroll
        for (int m = 1; m < 64; m <<= 1) {
#pragma unroll
            for (int r = 0; r < 4; ++r) {
                s0[r] += __shfl_xor(s0[r], m, 64);
                s1[r] += __shfl_xor(s1[r], m, 64);
            }
        }
        if (lane == 0) {
#pragma unroll
            for (int r = 0; r < 4; ++r) atomicAdd(&csum[cA * 4 + r], s0[r]);
            if (gbase + 640 > bnd) {
#pragma unroll
                for (int r = 0; r < 4; ++r) atomicAdd(&csum[(cA + 1) * 4 + r], s1[r]);
            }
        }
    }
    __syncthreads();

    if (t < 40) {
        int c = t >> 2, r = t & 3;
        out[(size_t)(rowbase + r) * 10 + c] = csum[t] * (1.0f / 30.0f);
    }
}

extern "C" void kernel_launch(void* const* d_in, const int* in_sizes, int n_in,
                              void* d_out, int out_size, void* d_ws, size_t ws_size,
                              hipStream_t stream) {
    const float* x = (const float*)d_in[0];
    const float* w1 = (const float*)d_in[1];
    const float* w2 = (const float*)d_in[2];
    const float* w3 = (const float*)d_in[3];
    const int* ia1 = (const int*)d_in[4];
    const int* ib1 = (const int*)d_in[5];
    const int* ia2 = (const int*)d_in[6];
    const int* ib2 = (const int*)d_in[7];
    const int* ia3 = (const int*)d_in[8];
    const int* ib3 = (const int*)d_in[9];
    float* out = (float*)d_out;

    // Workspace: bcM1 128K | bcM2 128K | d3M 160K (all 16B-aligned).
    char* p = (char*)d_ws;
    uint4* bcM1 = (uint4*)p;    p += (size_t)D2 * 16;
    uint4* bcM2 = (uint4*)p;    p += (size_t)D2 * 16;
    uint4* d3M = (uint4*)p;

    // >64KB dynamic LDS opt-in (host-side; graph-capture safe).
    hipFuncSetAttribute(reinterpret_cast<const void*>(fused_kernel),
                        hipFuncAttributeMaxDynamicSharedMemorySize, SM_BYTES);

    prep_kernel<<<(D2 + D3) / 64, 64, 0, stream>>>(
        w1, w2, w3, ia1, ib1, ia2, ib2, ia3, ib3, bcM1, bcM2, d3M);
    fused_kernel<<<B_ROWS / 4, 1024, SM_BYTES, stream>>>(x, bcM1, bcM2, d3M, out);
}

// Round 7
// 106.320 us; speedup vs baseline: 1.0217x; 1.0054x over previous
//
#include <hip/hip_runtime.h>
#include <hip/hip_fp16.h>
#include <stdint.h>

#define D0 1024
#define D1 8192
#define D2 8192
#define D3 10240
#define B_ROWS 4096

// LDS layout (bytes), 8 rows/block fp16 row-interleaved [gate][8 rows]=16B:
// xb 16K | h2 128K | csum 320 -> 144.3 KB, 1 block/CU (wave-capped anyway at
// 1024 thr; trades waves 32->16 for half the sequential blocks per CU).
#define SM_XB     0
#define SM_H2     16384
#define SM_CSUM   (16384 + 131072)
#define SM_BYTES  (16384 + 131072 + 320)

// softmax(w[16]) @ OP_COEF -> (c0,c1,c2,c3)
__device__ __forceinline__ float4 softmax_coef(const float* __restrict__ w) {
    const float4* wv = (const float4*)w;
    float4 q0 = wv[0], q1 = wv[1], q2 = wv[2], q3 = wv[3];
    float wa[16] = {q0.x, q0.y, q0.z, q0.w, q1.x, q1.y, q1.z, q1.w,
                    q2.x, q2.y, q2.z, q2.w, q3.x, q3.y, q3.z, q3.w};
    float m = wa[0];
#pragma unroll
    for (int i = 1; i < 16; ++i) m = fmaxf(m, wa[i]);
    float e[16], s = 0.f;
#pragma unroll
    for (int i = 0; i < 16; ++i) { e[i] = __expf(wa[i] - m); s += e[i]; }
    float inv = 1.f / s;
    static constexpr float OPC[16][4] = {
        {0.f, 0.f, 0.f, 0.f}, {0.f, 0.f, 0.f, 1.f}, {0.f, 1.f, 0.f, -1.f}, {0.f, 1.f, 0.f, 0.f},
        {0.f, 0.f, 1.f, -1.f}, {0.f, 0.f, 1.f, 0.f}, {0.f, 1.f, 1.f, -2.f}, {0.f, 1.f, 1.f, -1.f},
        {1.f, -1.f, -1.f, 1.f}, {1.f, -1.f, -1.f, 2.f}, {1.f, 0.f, -1.f, 0.f}, {1.f, 0.f, -1.f, 1.f},
        {1.f, -1.f, 0.f, 0.f}, {1.f, -1.f, 0.f, 1.f}, {1.f, 0.f, 0.f, -1.f}, {1.f, 0.f, 0.f, 0.f}};
    float c0 = 0.f, c1 = 0.f, c2 = 0.f, c3 = 0.f;
#pragma unroll
    for (int i = 0; i < 16; ++i) {  // 0/±1/±2 multiplies fold at compile time
        float p = e[i] * inv;
        c0 += p * OPC[i][0];
        c1 += p * OPC[i][1];
        c2 += p * OPC[i][2];
        c3 += p * OPC[i][3];
    }
    return make_float4(c0, c1, c2, c3);
}

__device__ __forceinline__ uint2 pack_coef(float4 c) {
    uint2 r;
    r.x = __builtin_bit_cast(uint32_t, __floats2half2_rn(c.x, c.y));
    r.y = __builtin_bit_cast(uint32_t, __floats2half2_rn(c.z, c.w));
    return r;
}

// prep: run-invariant metadata, packed for dwordx4 consumption.
//  bcM1[g] = (xiA, xiB, coO.lo, coO.hi)  xi* = packed x BYTE offsets (<<4,
//  bcM2[g] = (cA.lo, cA.hi, cB.lo, cB.hi) fits u16: max 1023*16)
//  d3M[g]  = (ei, co.lo, co.hi, 0)       ei = packed h2 ELEMENT indices
//                                        (byte offset would overflow u16)
__global__ __launch_bounds__(64) void prep_kernel(
    const float* __restrict__ w1, const float* __restrict__ w2,
    const float* __restrict__ w3,
    const int* __restrict__ ia1, const int* __restrict__ ib1,
    const int* __restrict__ ia2, const int* __restrict__ ib2,
    const int* __restrict__ ia3, const int* __restrict__ ib3,
    uint4* __restrict__ bcM1, uint4* __restrict__ bcM2,
    uint4* __restrict__ d3M) {
    int G = blockIdx.x * 64 + threadIdx.x;  // grid = (D2 + D3) / 64
    if (G < D2) {
        int g = G;
        int pa = ia2[g], pb = ib2[g];
        float4 cO = softmax_coef(w2 + (size_t)g * 16);
        float4 cA = softmax_coef(w1 + (size_t)pa * 16);
        float4 cB = softmax_coef(w1 + (size_t)pb * 16);
        uint32_t xiA = (uint32_t)(ia1[pa] << 4) | ((uint32_t)(ib1[pa] << 4) << 16);
        uint32_t xiB = (uint32_t)(ia1[pb] << 4) | ((uint32_t)(ib1[pb] << 4) << 16);
        uint2 o = pack_coef(cO), a = pack_coef(cA), b = pack_coef(cB);
        bcM1[g] = make_uint4(xiA, xiB, o.x, o.y);
        bcM2[g] = make_uint4(a.x, a.y, b.x, b.y);
    } else {
        int g = G - D2;
        float4 cO = softmax_coef(w3 + (size_t)g * 16);
        uint2 o = pack_coef(cO);
        uint32_t ei = (uint32_t)ia3[g] | ((uint32_t)ib3[g] << 16);
        d3M[g] = make_uint4(ei, o.x, o.y, 0u);
    }
}

// One gate for 8 rows (4x half2); compact coefs (c0c1, c2c3) broadcast here.
// h = (c0 + c2*b) + a*(c1 + c3*b): 12 v_pk_fma_f16 + 4 extracts.
__device__ __forceinline__ uint4 gate8(uint4 av, uint4 bv, uint2 cf) {
    __half2 p = __builtin_bit_cast(__half2, cf.x);  // (c0,c1)
    __half2 q = __builtin_bit_cast(__half2, cf.y);  // (c2,c3)
    __half2 c0 = __low2half2(p), c1 = __high2half2(p);
    __half2 c2 = __low2half2(q), c3 = __high2half2(q);
    uint4 r;
#pragma unroll
    for (int i = 0; i < 4; ++i) {
        __half2 a = __builtin_bit_cast(__half2, (&av.x)[i]);
        __half2 b = __builtin_bit_cast(__half2, (&bv.x)[i]);
        __half2 h = __hfma2(a, __hfma2(b, c3, c1), __hfma2(b, c2, c0));
        (&r.x)[i] = __builtin_bit_cast(uint32_t, h);
    }
    return r;
}

// Fused: layers 1+2 fused, then layer 3 + group-sum. One block = 8 rows,
// activations [gate][8 rows] fp16 (16 B) -> every gather is one
// ds_read_b128. Half the blocks of the 4-row shape: half the per-CU
// barrier/stage-A/tail overhead and ~20% fewer LDS cycles per row.
__global__ __launch_bounds__(1024, 4) void fused_kernel(
    const float* __restrict__ x, const uint4* __restrict__ bcM1,
    const uint4* __restrict__ bcM2, const uint4* __restrict__ d3M,
    float* __restrict__ out) {
    extern __shared__ char sm[];
    uint4* xb = (uint4*)(sm + SM_XB);
    float* csum = (float*)(sm + SM_CSUM);

    const int t = threadIdx.x;
    const int rowbase = blockIdx.x << 3;  // 8 rows per block
    const int tg = t << 1;  // first gate of this thread's pair

    // Preload iter-0 index metadata (latency hidden behind stage A + barrier).
    uint4 m1a_n = bcM1[tg];
    uint4 m1b_n = bcM1[tg + 1];

    // Stage A: 8 rows of x -> fp16, row-interleaved into xb (16 B/gate).
    {
        const float* xp = x + (size_t)rowbase * D0 + t;
        uint4 v;
#pragma unroll
        for (int i = 0; i < 4; ++i) {
            float va = xp[(size_t)(2 * i) * D0];
            float vb = xp[(size_t)(2 * i + 1) * D0];
            (&v.x)[i] = __builtin_bit_cast(uint32_t, __floats2half2_rn(va, vb));
        }
        xb[t] = v;
    }
    if (t < 80) csum[t] = 0.f;
    __syncthreads();

    // Stage BC: fused layers 1+2, 2 gates/thread/iter, 4 iters covers 8192.
#pragma unroll
    for (int k = 0; k < 4; ++k) {
        uint4 m1a = m1a_n, m1b = m1b_n;
        int g = tg + (k << 11);
        uint4 m2a = bcM2[g];
        uint4 m2b = bcM2[g + 1];
        if (k < 3) {  // depth-2 prefetch of the gather-address stream
            int gn = tg + ((k + 1) << 11);
            m1a_n = bcM1[gn];
            m1b_n = bcM1[gn + 1];
        }
        // 8 independent b128 gathers in flight.
        uint4 aa0 = *(const uint4*)(sm + (m1a.x & 0xffffu));
        uint4 ab0 = *(const uint4*)(sm + (m1a.x >> 16));
        uint4 ba0 = *(const uint4*)(sm + (m1a.y & 0xffffu));
        uint4 bb0 = *(const uint4*)(sm + (m1a.y >> 16));
        uint4 aa1 = *(const uint4*)(sm + (m1b.x & 0xffffu));
        uint4 ab1 = *(const uint4*)(sm + (m1b.x >> 16));
        uint4 ba1 = *(const uint4*)(sm + (m1b.y & 0xffffu));
        uint4 bb1 = *(const uint4*)(sm + (m1b.y >> 16));
        uint4 h0 = gate8(gate8(aa0, ab0, make_uint2(m2a.x, m2a.y)),
                         gate8(ba0, bb0, make_uint2(m2a.z, m2a.w)),
                         make_uint2(m1a.z, m1a.w));
        uint4 h1v = gate8(gate8(aa1, ab1, make_uint2(m2b.x, m2b.y)),
                          gate8(ba1, bb1, make_uint2(m2b.z, m2b.w)),
                          make_uint2(m1b.z, m1b.w));
        *(uint4*)(sm + SM_H2 + ((uint32_t)g << 4)) = h0;
        *(uint4*)(sm + SM_H2 + ((uint32_t)(g + 1) << 4)) = h1v;
    }
    __syncthreads();

    // Stage D: layer 3 + grouped sum, 2 gates/lane/iter, 5 iters x 128 gates.
    // Each 128-gate chunk lies entirely within one class (128 | 1024).
    {
        const int wv = t >> 6, lane = t & 63;
        const int gbase = wv * 640;
        const int cA = gbase >> 10;
        const int bnd = (cA + 1) << 10;
        float s0[8] = {0.f, 0.f, 0.f, 0.f, 0.f, 0.f, 0.f, 0.f};
        float s1[8] = {0.f, 0.f, 0.f, 0.f, 0.f, 0.f, 0.f, 0.f};
#pragma unroll
        for (int j = 0; j < 5; ++j) {
            int gc = gbase + (j << 7);
            int g = gc + (lane << 1);
            uint4 ma = d3M[g];
            uint4 mb = d3M[g + 1];
            uint4 av0 = *(const uint4*)(sm + SM_H2 + ((ma.x & 0xffffu) << 4));
            uint4 bv0 = *(const uint4*)(sm + SM_H2 + ((ma.x >> 16) << 4));
            uint4 av1 = *(const uint4*)(sm + SM_H2 + ((mb.x & 0xffffu) << 4));
            uint4 bv1 = *(const uint4*)(sm + SM_H2 + ((mb.x >> 16) << 4));
            uint4 h0 = gate8(av0, bv0, make_uint2(ma.y, ma.z));
            uint4 h1v = gate8(av1, bv1, make_uint2(mb.y, mb.z));
            float* s = (gc < bnd) ? s0 : s1;  // wave-uniform select
#pragma unroll
            for (int i = 0; i < 4; ++i) {
                __half2 pr = __hadd2(__builtin_bit_cast(__half2, (&h0.x)[i]),
                                     __builtin_bit_cast(__half2, (&h1v.x)[i]));
                s[2 * i] += __low2float(pr);
                s[2 * i + 1] += __high2float(pr);
            }
        }
#pragma unroll
        for (int m = 1; m < 64; m <<= 1) {
#pragma unroll
            for (int r = 0; r < 8; ++r) {
                s0[r] += __shfl_xor(s0[r], m, 64);
                s1[r] += __shfl_xor(s1[r], m, 64);
            }
        }
        if (lane == 0) {
#pragma unroll
            for (int r = 0; r < 8; ++r) atomicAdd(&csum[cA * 8 + r], s0[r]);
            if (gbase + 640 > bnd) {
#pragma unroll
                for (int r = 0; r < 8; ++r) atomicAdd(&csum[(cA + 1) * 8 + r], s1[r]);
            }
        }
    }
    __syncthreads();

    if (t < 80) {
        int c = t >> 3, r = t & 7;
        out[(size_t)(rowbase + r) * 10 + c] = csum[t] * (1.0f / 30.0f);
    }
}

extern "C" void kernel_launch(void* const* d_in, const int* in_sizes, int n_in,
                              void* d_out, int out_size, void* d_ws, size_t ws_size,
                              hipStream_t stream) {
    const float* x = (const float*)d_in[0];
    const float* w1 = (const float*)d_in[1];
    const float* w2 = (const float*)d_in[2];
    const float* w3 = (const float*)d_in[3];
    const int* ia1 = (const int*)d_in[4];
    const int* ib1 = (const int*)d_in[5];
    const int* ia2 = (const int*)d_in[6];
    const int* ib2 = (const int*)d_in[7];
    const int* ia3 = (const int*)d_in[8];
    const int* ib3 = (const int*)d_in[9];
    float* out = (float*)d_out;

    // Workspace: bcM1 128K | bcM2 128K | d3M 160K (all 16B-aligned).
    char* p = (char*)d_ws;
    uint4* bcM1 = (uint4*)p;    p += (size_t)D2 * 16;
    uint4* bcM2 = (uint4*)p;    p += (size_t)D2 * 16;
    uint4* d3M = (uint4*)p;

    // >64KB dynamic LDS opt-in (host-side; graph-capture safe). 144.3 KB
    // fits the 160 KB/CU pool.
    hipFuncSetAttribute(reinterpret_cast<const void*>(fused_kernel),
                        hipFuncAttributeMaxDynamicSharedMemorySize, SM_BYTES);

    prep_kernel<<<(D2 + D3) / 64, 64, 0, stream>>>(
        w1, w2, w3, ia1, ib1, ia2, ib2, ia3, ib3, bcM1, bcM2, d3M);
    fused_kernel<<<B_ROWS / 8, 1024, SM_BYTES, stream>>>(x, bcM1, bcM2, d3M, out);
}